// Round 1
// baseline (1592.591 us; speedup 1.0000x reference)
//
#include <hip/hip_runtime.h>

// ---------------------------------------------------------------------------
// Bidirectional GRU (B=128, T=512, E=H=256) + linear head.
// Phase 1: G[v][c] = emb[v] @ W_ih_d.T + b_ih (+ b_hh for r,z gates), bf16,
//          columns PERMUTED so that recurrence wave w owns gates
//          {r,z,n} x {lo,hi} for i in [32w, 32w+32).
// Phase 2: 16 WGs (2 dirs x 8 batch-groups of 16), 512 threads each.
//          W_hh lives in 192 VGPRs/lane as MFMA A-fragments (bf16).
//          Per step: hg^T = W_hh * h^T via 48 mfma_f32_16x16x32_bf16;
//          pointwise GRU fully in-lane (acc C-layout == permuted gate layout);
//          h (fp32) persists in registers; h->bf16 B-frags via 8 KB LDS.
// ---------------------------------------------------------------------------

typedef float f32x4 __attribute__((ext_vector_type(4)));
typedef short s16x8 __attribute__((ext_vector_type(8)));

#define VOCAB   30000
#define GCOLS   1536
#define HB_STR  272     // bf16 elements per h row (256 + pad, 16B-multiple)
#define HS_STR  260     // f32 elements per h row for epilogue

static __device__ __forceinline__ unsigned short f2bf(float f) {
    unsigned u = __builtin_bit_cast(unsigned, f);
    u += 0x7fffu + ((u >> 16) & 1u);            // RNE
    return (unsigned short)(u >> 16);
}
static __device__ __forceinline__ float bf_lo(unsigned v) {
    return __builtin_bit_cast(float, v << 16);
}
static __device__ __forceinline__ float bf_hi(unsigned v) {
    return __builtin_bit_cast(float, v & 0xffff0000u);
}
static __device__ __forceinline__ s16x8 pack_bf8(float4 a, float4 b) {
    s16x8 r;
    r[0] = (short)f2bf(a.x); r[1] = (short)f2bf(a.y);
    r[2] = (short)f2bf(a.z); r[3] = (short)f2bf(a.w);
    r[4] = (short)f2bf(b.x); r[5] = (short)f2bf(b.y);
    r[6] = (short)f2bf(b.z); r[7] = (short)f2bf(b.w);
    return r;
}
static __device__ __forceinline__ f32x4 mfma16(s16x8 a, s16x8 b, f32x4 c) {
    return __builtin_amdgcn_mfma_f32_16x16x32_bf16(a, b, c, 0, 0, 0);
}
static __device__ __forceinline__ float fast_sigmoid(float x) {
    return __builtin_amdgcn_rcpf(1.0f + __builtin_amdgcn_exp2f(-1.4426950408889634f * x));
}
static __device__ __forceinline__ float fast_tanh(float x) {
    return 1.0f - 2.0f * __builtin_amdgcn_rcpf(1.0f + __builtin_amdgcn_exp2f(2.8853900817779268f * x));
}

// permuted col c = d*768 + tl*16 + u, tl = 6*w + t,
// orig gate row = (t>>1)*256 + 32*w + ((t&1)<<4) + u
// t in {0,1}=r, {2,3}=z, {4,5}=n  (lo/hi 16-blocks)

// ---------------------------------------------------------------------------
// Phase 1: gate table.  grid (6 N-strips of 256 cols, 60 M-blocks of 512 rows)
// ---------------------------------------------------------------------------
__global__ __launch_bounds__(512, 2)
void gru_table_kernel(const float* __restrict__ emb,
                      const float* __restrict__ Wih_f, const float* __restrict__ bih_f,
                      const float* __restrict__ bhh_f,
                      const float* __restrict__ Wih_b, const float* __restrict__ bih_b,
                      const float* __restrict__ bhh_b,
                      unsigned short* __restrict__ G) {
    __shared__ unsigned short aS[16 * HB_STR];
    const int tid  = threadIdx.x;
    const int lane = tid & 63;
    const int w    = tid >> 6;       // wave 0..7
    const int u    = lane & 15;
    const int q    = lane >> 4;
    const int strip = blockIdx.x;    // 0..5
    const int by    = blockIdx.y;    // 0..59

    // B-fragments (weights) for this wave's 2 N-tiles, register resident.
    s16x8 breg[2][8];
    float beta[2];
    int   ntg_j[2];
#pragma unroll
    for (int j = 0; j < 2; ++j) {
        int ntg = strip * 16 + w * 2 + j;        // global N-tile 0..95
        ntg_j[j] = ntg;
        int dd = (ntg >= 48) ? 1 : 0;
        int tl = ntg - dd * 48;
        int wp = tl / 6;
        int t  = tl - wp * 6;
        int orig = (t >> 1) * 256 + 32 * wp + ((t & 1) << 4) + u;
        const float* Wih = dd ? Wih_b : Wih_f;
        const float* bih = dd ? bih_b : bih_f;
        const float* bhh = dd ? bhh_b : bhh_f;
        beta[j] = bih[orig] + ((t < 4) ? bhh[orig] : 0.0f);
#pragma unroll
        for (int kt = 0; kt < 8; ++kt) {
            const float* p = Wih + orig * 256 + kt * 32 + q * 8;
            float4 x0 = *(const float4*)p;
            float4 x1 = *(const float4*)(p + 4);
            breg[j][kt] = pack_bf8(x0, x1);
        }
    }

    for (int mt = 0; mt < 32; ++mt) {
        const int v0 = by * 512 + mt * 16;
        // stage 16 emb rows -> bf16 LDS (A-layout source)
        {
            int row = tid >> 5;
            int c8  = (tid & 31) * 8;
            int v   = v0 + row;
            float4 e0 = make_float4(0.f, 0.f, 0.f, 0.f), e1 = e0;
            if (v < VOCAB) {
                const float* p = emb + (size_t)v * 256 + c8;
                e0 = *(const float4*)p;
                e1 = *(const float4*)(p + 4);
            }
            unsigned short* dst = &aS[row * HB_STR + c8];
            dst[0] = f2bf(e0.x); dst[1] = f2bf(e0.y);
            dst[2] = f2bf(e0.z); dst[3] = f2bf(e0.w);
            dst[4] = f2bf(e1.x); dst[5] = f2bf(e1.y);
            dst[6] = f2bf(e1.z); dst[7] = f2bf(e1.w);
        }
        __syncthreads();

        f32x4 acc0 = {0.f, 0.f, 0.f, 0.f}, acc1 = acc0;
#pragma unroll
        for (int kt = 0; kt < 8; ++kt) {
            s16x8 af = *(const s16x8*)&aS[u * HB_STR + kt * 32 + q * 8];
            acc0 = mfma16(af, breg[0][kt], acc0);
            acc1 = mfma16(af, breg[1][kt], acc1);
        }
#pragma unroll
        for (int j = 0; j < 2; ++j) {
            f32x4 a = j ? acc1 : acc0;
#pragma unroll
            for (int r = 0; r < 4; ++r) {
                int v = v0 + q * 4 + r;
                if (v < VOCAB)
                    G[(size_t)v * GCOLS + ntg_j[j] * 16 + u] = f2bf(a[r] + beta[j]);
            }
        }
        __syncthreads();
    }
}

// ---------------------------------------------------------------------------
// Phase 2: recurrence. grid = 16 (dir = bx>>3, batch group = bx&7), 512 thr.
// ---------------------------------------------------------------------------
__global__ __launch_bounds__(512, 2)
void gru_rnn_kernel(const int* __restrict__ inp,
                    const float* __restrict__ Whh_f, const float* __restrict__ bhh_f,
                    const float* __restrict__ Whh_b, const float* __restrict__ bhh_b,
                    const float* __restrict__ W_lin, const float* __restrict__ b_lin,
                    const unsigned short* __restrict__ G,
                    float* __restrict__ out) {
    __shared__ int            toks[16][513];       // +1 pad: conflict-free
    __shared__ unsigned short hB[16 * HB_STR];     // h (bf16) B-operand layout
    __shared__ float          bhn_s[256];
    __shared__ float          hs[16 * HS_STR];     // final h fp32 for epilogue

    const int tid  = threadIdx.x;
    const int lane = tid & 63;
    const int w    = tid >> 6;          // wave 0..7
    const int b    = lane & 15;         // batch within group (B-frag n / C col)
    const int q    = lane >> 4;
    const int d    = blockIdx.x >> 3;   // 0 fwd, 1 bwd
    const int b0   = (blockIdx.x & 7) * 16;

    const float* Whh = d ? Whh_b : Whh_f;
    const float* bhh = d ? bhh_b : bhh_f;

    // W_hh as A-fragments, register resident: wave w -> tiles {r,z,n}x{lo,hi}
    s16x8 wreg[6][8];
#pragma unroll
    for (int t = 0; t < 6; ++t) {
        int orig = (t >> 1) * 256 + 32 * w + ((t & 1) << 4) + b;  // lane&15 = m
#pragma unroll
        for (int kt = 0; kt < 8; ++kt) {
            const float* p = Whh + orig * 256 + kt * 32 + q * 8;
            float4 x0 = *(const float4*)p;
            float4 x1 = *(const float4*)(p + 4);
            wreg[t][kt] = pack_bf8(x0, x1);
        }
    }

    for (int i = tid; i < 16 * 512; i += 512) {
        int bb = i >> 9, t = i & 511;
        toks[bb][t] = inp[(b0 + bb) * 512 + t];
    }
    for (int i = tid; i < 16 * HB_STR; i += 512) hB[i] = 0;   // h0 = 0
    if (tid < 256) bhn_s[tid] = bhh[512 + tid];
    __syncthreads();

    const int i0 = 32 * w + 4 * q;                 // this lane's hidden base
    const f32x4 bhn_lo = *(const f32x4*)&bhn_s[i0];
    const f32x4 bhn_hi = *(const f32x4*)&bhn_s[i0 + 16];

    float hreg[8];
#pragma unroll
    for (int i = 0; i < 8; ++i) hreg[i] = 0.f;

    const int hboff = b * HB_STR + q * 8;
    const size_t gcol = (size_t)d * 768 + 96 * w + 4 * q;

    for (int ts = 0; ts < 512; ++ts) {
        const int tt  = d ? (511 - ts) : ts;
        const int tok = toks[b][tt];
        // xg gather (r,z,n lo/hi), 6 x 8B, issued early to hide L2/L3 latency
        const uint2* gp = (const uint2*)(G + (size_t)tok * GCOLS + gcol);
        const uint2 xr0 = gp[0],  xr1 = gp[4];
        const uint2 xz0 = gp[8],  xz1 = gp[12];
        const uint2 xn0 = gp[16], xn1 = gp[20];

        f32x4 acc0 = {0.f, 0.f, 0.f, 0.f}, acc1 = acc0, acc2 = acc0, acc3 = acc0;
        f32x4 acc4 = bhn_lo, acc5 = bhn_hi;     // fold b_hh_n via acc init
#pragma unroll
        for (int kt = 0; kt < 8; ++kt) {
            s16x8 hf = *(const s16x8*)&hB[hboff + kt * 32];
            acc0 = mfma16(wreg[0][kt], hf, acc0);
            acc1 = mfma16(wreg[1][kt], hf, acc1);
            acc2 = mfma16(wreg[2][kt], hf, acc2);
            acc3 = mfma16(wreg[3][kt], hf, acc3);
            acc4 = mfma16(wreg[4][kt], hf, acc4);
            acc5 = mfma16(wreg[5][kt], hf, acc5);
        }
        // in-lane GRU pointwise: lane holds r/z/n for (batch b, i0+r, i0+16+r)
#pragma unroll
        for (int g = 0; g < 2; ++g) {
            const uint2 xr = g ? xr1 : xr0;
            const uint2 xz = g ? xz1 : xz0;
            const uint2 xn = g ? xn1 : xn0;
            const f32x4 ar = g ? acc1 : acc0;
            const f32x4 az = g ? acc3 : acc2;
            const f32x4 an = g ? acc5 : acc4;
            float xrf[4] = {bf_lo(xr.x), bf_hi(xr.x), bf_lo(xr.y), bf_hi(xr.y)};
            float xzf[4] = {bf_lo(xz.x), bf_hi(xz.x), bf_lo(xz.y), bf_hi(xz.y)};
            float xnf[4] = {bf_lo(xn.x), bf_hi(xn.x), bf_lo(xn.y), bf_hi(xn.y)};
#pragma unroll
            for (int r = 0; r < 4; ++r) {
                float rg = fast_sigmoid(xrf[r] + ar[r]);
                float zg = fast_sigmoid(xzf[r] + az[r]);
                float ng = fast_tanh(xnf[r] + rg * an[r]);
                float h  = hreg[g * 4 + r];
                hreg[g * 4 + r] = ng + zg * (h - ng);
            }
        }
        __syncthreads();   // everyone done reading hB for this step
        {
            unsigned p0 = (unsigned)f2bf(hreg[0]) | ((unsigned)f2bf(hreg[1]) << 16);
            unsigned p1 = (unsigned)f2bf(hreg[2]) | ((unsigned)f2bf(hreg[3]) << 16);
            unsigned p2 = (unsigned)f2bf(hreg[4]) | ((unsigned)f2bf(hreg[5]) << 16);
            unsigned p3 = (unsigned)f2bf(hreg[6]) | ((unsigned)f2bf(hreg[7]) << 16);
            *(uint2*)&hB[b * HB_STR + i0]      = make_uint2(p0, p1);
            *(uint2*)&hB[b * HB_STR + i0 + 16] = make_uint2(p2, p3);
        }
        __syncthreads();   // h_new visible before next step's reads
    }

    // epilogue: out[b][c] += h_d[b] . W_lin[c, d*256:+256]  (+ b_lin once)
    {
        f32x4 lo = {hreg[0], hreg[1], hreg[2], hreg[3]};
        f32x4 hi = {hreg[4], hreg[5], hreg[6], hreg[7]};
        *(f32x4*)&hs[b * HS_STR + i0]      = lo;
        *(f32x4*)&hs[b * HS_STR + i0 + 16] = hi;
    }
    __syncthreads();
    if (tid < 160) {
        int bb = tid / 10;
        int c  = tid - bb * 10;
        float acc = d ? 0.0f : b_lin[c];
        const float* wl = W_lin + c * 512 + d * 256;
        const float* hp = &hs[bb * HS_STR];
        for (int i = 0; i < 256; ++i) acc += hp[i] * wl[i];
        atomicAdd(&out[(b0 + bb) * 10 + c], acc);
    }
}

// ---------------------------------------------------------------------------
extern "C" void kernel_launch(void* const* d_in, const int* in_sizes, int n_in,
                              void* d_out, int out_size, void* d_ws, size_t ws_size,
                              hipStream_t stream) {
    const int*   inp   = (const int*)d_in[0];
    const float* emb   = (const float*)d_in[1];
    const float* Wih_f = (const float*)d_in[2];
    const float* Whh_f = (const float*)d_in[3];
    const float* bih_f = (const float*)d_in[4];
    const float* bhh_f = (const float*)d_in[5];
    const float* Wih_b = (const float*)d_in[6];
    const float* Whh_b = (const float*)d_in[7];
    const float* bih_b = (const float*)d_in[8];
    const float* bhh_b = (const float*)d_in[9];
    const float* W_lin = (const float*)d_in[10];
    const float* b_lin = (const float*)d_in[11];
    float* out = (float*)d_out;
    unsigned short* G = (unsigned short*)d_ws;   // 30000*1536*2 B = 92.16 MB

    hipMemsetAsync(d_out, 0, (size_t)out_size * sizeof(float), stream);
    hipLaunchKernelGGL(gru_table_kernel, dim3(6, 60), dim3(512), 0, stream,
                       emb, Wih_f, bih_f, bhh_f, Wih_b, bih_b, bhh_b, G);
    hipLaunchKernelGGL(gru_rnn_kernel, dim3(16), dim3(512), 0, stream,
                       inp, Whh_f, bhh_f, Whh_b, bhh_b, W_lin, b_lin, G, out);
}

// Round 2
// 1557.434 us; speedup vs baseline: 1.0226x; 1.0226x over previous
//
#include <hip/hip_runtime.h>

// ---------------------------------------------------------------------------
// Bidirectional GRU (B=128, T=512, E=H=256) + linear head.
// Phase 1: G[v][c] = (emb[v] @ W_ih_d.T + b_ih (+ b_hh for r,z)) * gate_scale
//          bf16, columns PERMUTED per recurrence wave layout. Gate scales
//          baked in: r,z cols * -log2(e)  (sigmoid -> rcp(1+exp2(x)));
//          n cols * 2*log2(e)             (tanh    -> 1-2*rcp(1+exp2(x))).
// Phase 2: 16 WGs (2 dirs x 8 batch-groups of 16), 512 threads.
//          W_hh (same scales baked) in regs as MFMA A-fragments.
//          Per step: 48 mfma_16x16x32_bf16, fully in-lane pointwise,
//          h double-buffered in LDS (ONE barrier/step), and the G-table
//          gather software-pipelined one full step ahead.
// ---------------------------------------------------------------------------

typedef float f32x4 __attribute__((ext_vector_type(4)));
typedef short s16x8 __attribute__((ext_vector_type(8)));

#define VOCAB   30000
#define GCOLS   1536
#define HB_STR  280     // bf16 elems per h row; 560 B ≡ 48 mod 128 -> b128 conflict-free
#define HBUF    (16 * HB_STR)
#define HS_STR  260     // f32 elements per h row for epilogue
#define SRF     (-1.4426950408889634f)   // -log2(e), sigmoid gates
#define SNF     (2.8853900817779268f)    // 2*log2(e), tanh gate

#if defined(__has_builtin)
#if __has_builtin(__builtin_amdgcn_cvt_pk_bf16_f32)
#define HAVE_PK 1
#endif
#endif

static __device__ __forceinline__ unsigned short f2bf(float f) {
    unsigned u = __builtin_bit_cast(unsigned, f);
    u += 0x7fffu + ((u >> 16) & 1u);            // RNE
    return (unsigned short)(u >> 16);
}
#ifdef HAVE_PK
typedef __bf16 bf16x2_t __attribute__((ext_vector_type(2)));
static __device__ __forceinline__ unsigned pk2(float a, float b) {
    bf16x2_t v = __builtin_amdgcn_cvt_pk_bf16_f32(a, b);
    return __builtin_bit_cast(unsigned, v);
}
#else
static __device__ __forceinline__ unsigned pk2(float a, float b) {
    return (unsigned)f2bf(a) | ((unsigned)f2bf(b) << 16);
}
#endif
static __device__ __forceinline__ float bf_lo(unsigned v) {
    return __builtin_bit_cast(float, v << 16);
}
static __device__ __forceinline__ float bf_hi(unsigned v) {
    return __builtin_bit_cast(float, v & 0xffff0000u);
}
static __device__ __forceinline__ s16x8 pack_bf8(float4 a, float4 b, float s) {
    union { s16x8 v; unsigned u[4]; } r;
    r.u[0] = pk2(a.x * s, a.y * s); r.u[1] = pk2(a.z * s, a.w * s);
    r.u[2] = pk2(b.x * s, b.y * s); r.u[3] = pk2(b.z * s, b.w * s);
    return r.v;
}
static __device__ __forceinline__ f32x4 mfma16(s16x8 a, s16x8 b, f32x4 c) {
    return __builtin_amdgcn_mfma_f32_16x16x32_bf16(a, b, c, 0, 0, 0);
}
static __device__ __forceinline__ float sig2(float x) {      // 1/(1+2^x)
    return __builtin_amdgcn_rcpf(1.0f + __builtin_amdgcn_exp2f(x));
}

// permuted col c = d*768 + tl*16 + u, tl = 6*w + t,
// orig gate row = (t>>1)*256 + 32*w + ((t&1)<<4) + u
// t in {0,1}=r, {2,3}=z, {4,5}=n  (lo/hi 16-blocks)

// ---------------------------------------------------------------------------
// Phase 1: gate table.  grid (6 N-strips of 256 cols, 60 M-blocks of 512 rows)
// ---------------------------------------------------------------------------
__global__ __launch_bounds__(512, 2)
void gru_table_kernel(const float* __restrict__ emb,
                      const float* __restrict__ Wih_f, const float* __restrict__ bih_f,
                      const float* __restrict__ bhh_f,
                      const float* __restrict__ Wih_b, const float* __restrict__ bih_b,
                      const float* __restrict__ bhh_b,
                      unsigned short* __restrict__ G) {
    __shared__ unsigned short aS[16 * HB_STR];
    const int tid  = threadIdx.x;
    const int lane = tid & 63;
    const int w    = tid >> 6;       // wave 0..7
    const int u    = lane & 15;
    const int q    = lane >> 4;
    const int strip = blockIdx.x;    // 0..5
    const int by    = blockIdx.y;    // 0..59

    // B-fragments (weights, pre-scaled) for this wave's 2 N-tiles.
    s16x8 breg[2][8];
    float beta[2];
    int   ntg_j[2];
#pragma unroll
    for (int j = 0; j < 2; ++j) {
        int ntg = strip * 16 + w * 2 + j;        // global N-tile 0..95
        ntg_j[j] = ntg;
        int dd = (ntg >= 48) ? 1 : 0;
        int tl = ntg - dd * 48;
        int wp = tl / 6;
        int t  = tl - wp * 6;
        int orig = (t >> 1) * 256 + 32 * wp + ((t & 1) << 4) + u;
        const float* Wih = dd ? Wih_b : Wih_f;
        const float* bih = dd ? bih_b : bih_f;
        const float* bhh = dd ? bhh_b : bhh_f;
        const float scl = (t < 4) ? SRF : SNF;
        beta[j] = (bih[orig] + ((t < 4) ? bhh[orig] : 0.0f)) * scl;
#pragma unroll
        for (int kt = 0; kt < 8; ++kt) {
            const float* p = Wih + orig * 256 + kt * 32 + q * 8;
            float4 x0 = *(const float4*)p;
            float4 x1 = *(const float4*)(p + 4);
            breg[j][kt] = pack_bf8(x0, x1, scl);
        }
    }

    for (int mt = 0; mt < 32; ++mt) {
        const int v0 = by * 512 + mt * 16;
        // stage 16 emb rows -> bf16 LDS (A-layout source)
        {
            int row = tid >> 5;
            int c8  = (tid & 31) * 8;
            int v   = v0 + row;
            float4 e0 = make_float4(0.f, 0.f, 0.f, 0.f), e1 = e0;
            if (v < VOCAB) {
                const float* p = emb + (size_t)v * 256 + c8;
                e0 = *(const float4*)p;
                e1 = *(const float4*)(p + 4);
            }
            unsigned* dp = (unsigned*)&aS[row * HB_STR + c8];
            dp[0] = pk2(e0.x, e0.y); dp[1] = pk2(e0.z, e0.w);
            dp[2] = pk2(e1.x, e1.y); dp[3] = pk2(e1.z, e1.w);
        }
        __syncthreads();

        f32x4 acc0 = {0.f, 0.f, 0.f, 0.f}, acc1 = acc0;
#pragma unroll
        for (int kt = 0; kt < 8; ++kt) {
            s16x8 af = *(const s16x8*)&aS[u * HB_STR + kt * 32 + q * 8];
            acc0 = mfma16(af, breg[0][kt], acc0);
            acc1 = mfma16(af, breg[1][kt], acc1);
        }
#pragma unroll
        for (int j = 0; j < 2; ++j) {
            f32x4 a = j ? acc1 : acc0;
#pragma unroll
            for (int r = 0; r < 4; ++r) {
                int v = v0 + q * 4 + r;
                if (v < VOCAB)
                    G[(size_t)v * GCOLS + ntg_j[j] * 16 + u] = f2bf(a[r] + beta[j]);
            }
        }
        __syncthreads();
    }
}

// ---------------------------------------------------------------------------
// Phase 2: recurrence. grid = 16 (dir = bx>>3, batch group = bx&7), 512 thr.
// ---------------------------------------------------------------------------
__global__ __launch_bounds__(512, 2)
void gru_rnn_kernel(const int* __restrict__ inp,
                    const float* __restrict__ Whh_f, const float* __restrict__ bhh_f,
                    const float* __restrict__ Whh_b, const float* __restrict__ bhh_b,
                    const float* __restrict__ W_lin, const float* __restrict__ b_lin,
                    const unsigned short* __restrict__ G,
                    float* __restrict__ out) {
    __shared__ int            toks[16][513];       // +1 pad: conflict-free
    __shared__ unsigned short hB[2 * HBUF];        // double-buffered h (bf16)
    __shared__ float          bhn_s[256];
    __shared__ float          hs[16 * HS_STR];     // final h fp32 for epilogue

    const int tid  = threadIdx.x;
    const int lane = tid & 63;
    const int w    = tid >> 6;          // wave 0..7
    const int b    = lane & 15;         // batch within group (B-frag n / C col)
    const int q    = lane >> 4;
    const int d    = blockIdx.x >> 3;   // 0 fwd, 1 bwd
    const int b0   = (blockIdx.x & 7) * 16;

    const float* Whh = d ? Whh_b : Whh_f;
    const float* bhh = d ? bhh_b : bhh_f;

    // W_hh as A-fragments (pre-scaled), register resident.
    s16x8 wreg[6][8];
#pragma unroll
    for (int t = 0; t < 6; ++t) {
        int orig = (t >> 1) * 256 + 32 * w + ((t & 1) << 4) + b;  // lane&15 = m
        const float scl = (t < 4) ? SRF : SNF;
#pragma unroll
        for (int kt = 0; kt < 8; ++kt) {
            const float* p = Whh + orig * 256 + kt * 32 + q * 8;
            float4 x0 = *(const float4*)p;
            float4 x1 = *(const float4*)(p + 4);
            wreg[t][kt] = pack_bf8(x0, x1, scl);
        }
    }

    for (int i = tid; i < 16 * 512; i += 512) {
        int bb = i >> 9, t = i & 511;
        toks[bb][t] = inp[(b0 + bb) * 512 + t];
    }
    for (int i = tid; i < 2 * HBUF; i += 512) hB[i] = 0;   // h0 = 0
    if (tid < 256) bhn_s[tid] = SNF * bhh[512 + tid];
    __syncthreads();

    const int i0    = 32 * w + 4 * q;              // this lane's hidden base
    const int hboff = b * HB_STR + q * 8;
    const size_t gcol = (size_t)d * 768 + 96 * w + 4 * q;

    float hreg[8];
#pragma unroll
    for (int i = 0; i < 8; ++i) hreg[i] = 0.f;

    // prologue: issue step-0 gather, stage step-1 token
    uint2 xr0, xr1, xz0, xz1, xn0, xn1;
    {
        int tok0 = toks[b][d ? 511 : 0];
        const uint2* gp = (const uint2*)(G + (size_t)tok0 * GCOLS + gcol);
        xr0 = gp[0];  xr1 = gp[4];
        xz0 = gp[8];  xz1 = gp[12];
        xn0 = gp[16]; xn1 = gp[20];
    }
    int tok_nxt = toks[b][d ? 510 : 1];

#pragma unroll 2
    for (int ts = 0; ts < 512; ++ts) {
        const int rb = (ts & 1) * HBUF;
        f32x4 acc0 = {0.f, 0.f, 0.f, 0.f}, acc1 = acc0, acc2 = acc0, acc3 = acc0;
        f32x4 acc4 = *(const f32x4*)&bhn_s[i0];        // b_hh_n * SNF (broadcast)
        f32x4 acc5 = *(const f32x4*)&bhn_s[i0 + 16];
#pragma unroll
        for (int kt = 0; kt < 8; ++kt) {
            s16x8 hf = *(const s16x8*)&hB[rb + hboff + kt * 32];
            acc0 = mfma16(wreg[0][kt], hf, acc0);
            acc1 = mfma16(wreg[1][kt], hf, acc1);
            acc2 = mfma16(wreg[2][kt], hf, acc2);
            acc3 = mfma16(wreg[3][kt], hf, acc3);
            acc4 = mfma16(wreg[4][kt], hf, acc4);
            acc5 = mfma16(wreg[5][kt], hf, acc5);
        }
        // unpack current xg, immediately re-issue next step's gather into the
        // same registers (loads stay in flight across s_barrier: ~full-step cover)
        const uint2* gp = (const uint2*)(G + (size_t)tok_nxt * GCOLS + gcol);
        float xrf[8] = {bf_lo(xr0.x), bf_hi(xr0.x), bf_lo(xr0.y), bf_hi(xr0.y),
                        bf_lo(xr1.x), bf_hi(xr1.x), bf_lo(xr1.y), bf_hi(xr1.y)};
        xr0 = gp[0];  xr1 = gp[4];
        float xzf[8] = {bf_lo(xz0.x), bf_hi(xz0.x), bf_lo(xz0.y), bf_hi(xz0.y),
                        bf_lo(xz1.x), bf_hi(xz1.x), bf_lo(xz1.y), bf_hi(xz1.y)};
        xz0 = gp[8];  xz1 = gp[12];
        float xnf[8] = {bf_lo(xn0.x), bf_hi(xn0.x), bf_lo(xn0.y), bf_hi(xn0.y),
                        bf_lo(xn1.x), bf_hi(xn1.x), bf_lo(xn1.y), bf_hi(xn1.y)};
        xn0 = gp[16]; xn1 = gp[20];
        {
            int s2 = ts + 2; if (s2 > 511) s2 = 511;
            tok_nxt = toks[b][d ? 511 - s2 : s2];
        }
        // in-lane GRU pointwise (scales pre-baked: all gates are sig2 forms)
#pragma unroll
        for (int g = 0; g < 2; ++g) {
            const f32x4 ar = g ? acc1 : acc0;
            const f32x4 az = g ? acc3 : acc2;
            const f32x4 an = g ? acc5 : acc4;
#pragma unroll
            for (int r = 0; r < 4; ++r) {
                const int i = g * 4 + r;
                float rg = sig2(xrf[i] + ar[r]);
                float zg = sig2(xzf[i] + az[r]);
                float tg = sig2(fmaf(rg, an[r], xnf[i]));
                float ng = fmaf(-2.0f, tg, 1.0f);
                hreg[i] = fmaf(zg, hreg[i] - ng, ng);
            }
        }
        // write h_new to the other buffer; ONE barrier per step
        {
            unsigned p0 = pk2(hreg[0], hreg[1]);
            unsigned p1 = pk2(hreg[2], hreg[3]);
            unsigned p2 = pk2(hreg[4], hreg[5]);
            unsigned p3 = pk2(hreg[6], hreg[7]);
            unsigned short* wb = &hB[((ts + 1) & 1) * HBUF + b * HB_STR + i0];
            *(uint2*)wb        = make_uint2(p0, p1);
            *(uint2*)(wb + 16) = make_uint2(p2, p3);
        }
        __syncthreads();
    }

    // epilogue: out[b][c] += h_d[b] . W_lin[c, d*256:+256]  (+ b_lin once)
    {
        f32x4 lo = {hreg[0], hreg[1], hreg[2], hreg[3]};
        f32x4 hi = {hreg[4], hreg[5], hreg[6], hreg[7]};
        *(f32x4*)&hs[b * HS_STR + i0]      = lo;
        *(f32x4*)&hs[b * HS_STR + i0 + 16] = hi;
    }
    __syncthreads();
    if (tid < 160) {
        int bb = tid / 10;
        int c  = tid - bb * 10;
        float acc = d ? 0.0f : b_lin[c];
        const float* wl = W_lin + c * 512 + d * 256;
        const float* hp = &hs[bb * HS_STR];
        for (int i = 0; i < 256; ++i) acc += hp[i] * wl[i];
        atomicAdd(&out[(b0 + bb) * 10 + c], acc);
    }
}

// ---------------------------------------------------------------------------
extern "C" void kernel_launch(void* const* d_in, const int* in_sizes, int n_in,
                              void* d_out, int out_size, void* d_ws, size_t ws_size,
                              hipStream_t stream) {
    const int*   inp   = (const int*)d_in[0];
    const float* emb   = (const float*)d_in[1];
    const float* Wih_f = (const float*)d_in[2];
    const float* Whh_f = (const float*)d_in[3];
    const float* bih_f = (const float*)d_in[4];
    const float* bhh_f = (const float*)d_in[5];
    const float* Wih_b = (const float*)d_in[6];
    const float* Whh_b = (const float*)d_in[7];
    const float* bih_b = (const float*)d_in[8];
    const float* bhh_b = (const float*)d_in[9];
    const float* W_lin = (const float*)d_in[10];
    const float* b_lin = (const float*)d_in[11];
    float* out = (float*)d_out;
    unsigned short* G = (unsigned short*)d_ws;   // 30000*1536*2 B = 92.16 MB

    hipMemsetAsync(d_out, 0, (size_t)out_size * sizeof(float), stream);
    hipLaunchKernelGGL(gru_table_kernel, dim3(6, 60), dim3(512), 0, stream,
                       emb, Wih_f, bih_f, bhh_f, Wih_b, bih_b, bhh_b, G);
    hipLaunchKernelGGL(gru_rnn_kernel, dim3(16), dim3(512), 0, stream,
                       inp, Whh_f, bhh_f, Whh_b, bhh_b, W_lin, b_lin, G, out);
}